// Round 7
// baseline (739.877 us; speedup 1.0000x reference)
//
#include <hip/hip_runtime.h>

#define N_NODES  100000
#define N_EDGES  3200000
#define N_GRAPHS 3200

// CSR-build constants
#define NBLK 200            // edge-chunk blocks
#define EB   16000          // edges per chunk (NBLK*EB == N_EDGES)
#define BSH  7              // bucket = dst >> 7  (128 nodes/bucket)
#define NB   ((N_NODES + 127) >> BSH)   // 782 buckets
#define BCAP 5120           // max edges per bucket staged in LDS
#define NT   25             // src tiles (src>>12 -> 0..24)
#define TSH  12
#define TP   33             // padded tile stride in LDS (bank-conflict pad)

typedef __attribute__((ext_vector_type(8))) short bf16x8;
typedef __attribute__((ext_vector_type(4))) float f32x4;

// ---------------- bf16 helpers ----------------
__device__ __forceinline__ float bf2f(unsigned short u) {
    return __uint_as_float(((unsigned)u) << 16);
}
__device__ __forceinline__ unsigned short f2bf(float f) {
    unsigned u = __float_as_uint(f);
    u += 0x7fffu + ((u >> 16) & 1u);   // RNE
    return (unsigned short)(u >> 16);
}

// ================= CSR build (counting sort, no global atomics) =================

__global__ __launch_bounds__(256, 4)
void hist_kernel(const int* __restrict__ dst, int* __restrict__ hist) {
    __shared__ int lh[NB];
    int blk = blockIdx.x, t = threadIdx.x;
    for (int b = t; b < NB; b += 256) lh[b] = 0;
    __syncthreads();
    int e0 = blk * EB;
    for (int i = t; i < EB; i += 256)
        atomicAdd(&lh[dst[e0 + i] >> BSH], 1);
    __syncthreads();
    for (int b = t; b < NB; b += 256) hist[b * NBLK + blk] = lh[b];
}

__global__ void bucket_tot_kernel(const int* __restrict__ hist, int* __restrict__ tot) {
    int b = blockIdx.x, l = threadIdx.x;   // 64 threads
    int s = 0;
    for (int k = l; k < NBLK; k += 64) s += hist[b * NBLK + k];
    for (int off = 32; off; off >>= 1) s += __shfl_down(s, off);
    if (l == 0) tot[b] = s;
}

__global__ void bucket_scan_kernel(const int* __restrict__ tot, int* __restrict__ bucketStart) {
    __shared__ int part[256];
    int t = threadIdx.x;
    int chunk = (NB + 255) / 256;
    int lo = t * chunk; if (lo > NB) lo = NB;
    int hi = lo + chunk; if (hi > NB) hi = NB;
    int s = 0;
    for (int i = lo; i < hi; ++i) s += tot[i];
    part[t] = s;
    __syncthreads();
    for (int off = 1; off < 256; off <<= 1) {
        int v = part[t];
        int a = (t >= off) ? part[t - off] : 0;
        __syncthreads();
        part[t] = v + a;
        __syncthreads();
    }
    int run = (t == 0) ? 0 : part[t - 1];
    for (int i = lo; i < hi; ++i) { bucketStart[i] = run; run += tot[i]; }
    if (t == 255) bucketStart[NB] = run;
}

__global__ void bucket_base_kernel(int* __restrict__ hist, const int* __restrict__ bucketStart) {
    int b = blockIdx.x * blockDim.x + threadIdx.x;
    if (b >= NB) return;
    int run = bucketStart[b];
    int* row = hist + b * NBLK;
#pragma unroll 4
    for (int k = 0; k < NBLK; ++k) { int v = row[k]; row[k] = run; run += v; }
}

__global__ __launch_bounds__(256, 4)
void scatter1_kernel(const int* __restrict__ src, const int* __restrict__ dst,
                     const int* __restrict__ base,
                     int* __restrict__ sdst, int* __restrict__ ssrc) {
    __shared__ int lcur[NB];
    int blk = blockIdx.x, t = threadIdx.x;
    for (int b = t; b < NB; b += 256) lcur[b] = base[b * NBLK + blk];
    __syncthreads();
    int e0 = blk * EB;
    for (int i = t; i < EB; i += 256) {
        int d = dst[e0 + i], s = src[e0 + i];
        int pos = atomicAdd(&lcur[d >> BSH], 1);
        sdst[pos] = d;
        ssrc[pos] = s;
    }
}

// Per-bucket node-level CSR with per-dst lists SORTED BY SRC-TILE.
// Emits tileoff[n][0..25] (26 ints per node: tile starts + end), dis, csr_src.
__global__ __launch_bounds__(256, 1)
void csr2_kernel(const int* __restrict__ sdst, const int* __restrict__ ssrc,
                 const int* __restrict__ bucketStart,
                 int* __restrict__ tileoff, float* __restrict__ dis,
                 int* __restrict__ csr_src) {
    __shared__ int lkey[BCAP];
    __shared__ int lsrc[BCAP];
    __shared__ int lh[128 * TP];
    __shared__ int lc[128 * TP];
    __shared__ int loff[128], ldeg[128];
    int b = blockIdx.x, t = threadIdx.x;
    int n0 = b << BSH;
    int e0 = bucketStart[b], e1 = bucketStart[b + 1];
    int cnt = e1 - e0; if (cnt > BCAP) cnt = BCAP;
    for (int i = t; i < cnt; i += 256) {
        int d = sdst[e0 + i] - n0;          // 0..127
        int s = ssrc[e0 + i];
        lkey[i] = d * TP + (s >> TSH);      // (dst, tile) key
        lsrc[i] = s;
    }
    for (int i = t; i < 128 * TP; i += 256) lh[i] = 0;
    __syncthreads();
    for (int i = t; i < cnt; i += 256) atomicAdd(&lh[lkey[i]], 1);
    __syncthreads();
    if (t < 128) {
        int run = 0;
#pragma unroll
        for (int p = 0; p < NT; ++p) { lc[t * TP + p] = run; run += lh[t * TP + p]; }
        ldeg[t] = run;
        loff[t] = run;
    }
    __syncthreads();
    for (int off = 1; off < 128; off <<= 1) {   // Hillis-Steele inclusive scan over deg
        int v = 0;
        if (t < 128) { v = loff[t]; if (t >= off) v += loff[t - off]; }
        __syncthreads();
        if (t < 128) loff[t] = v;
        __syncthreads();
    }
    if (t < 128) {
        int excl = loff[t] - ldeg[t];
        int n = n0 + t;
        if (n < N_NODES) {
#pragma unroll
            for (int p = 0; p < NT; ++p) {
                int v = lc[t * TP + p] + excl;
                lc[t * TP + p] = v;
                tileoff[(size_t)n * 26 + p] = e0 + v;
            }
            tileoff[(size_t)n * 26 + NT] = e0 + excl + ldeg[t];
            dis[n] = rsqrtf((float)ldeg[t] + 1.0f);
        } else {
#pragma unroll
            for (int p = 0; p < NT; ++p) lc[t * TP + p] += excl;
        }
    }
    __syncthreads();
    for (int i = t; i < cnt; i += 256) {
        int pos = atomicAdd(&lc[lkey[i]], 1);
        csr_src[e0 + pos] = lsrc[i];
    }
}

// ---------------- pack W[Krows x N] fp32 -> split bf16 planes in MFMA B-frag layout --------
// element j of lane l of k-step s of n-tile t at ((t*KS + s)*64 + l)*8 + j
// maps to W[k = s*32 + (l>>4)*8 + j][n = t*16 + (l&15)]; k >= Krows -> 0 (zero pad)
template<int K, int N>
__global__ void pack_w_kernel(const float* __restrict__ W, int Krows,
                              unsigned short* __restrict__ hi,
                              unsigned short* __restrict__ lo) {
    constexpr int KS = K / 32;
    int idx = blockIdx.x * blockDim.x + threadIdx.x;
    if (idx >= (N / 16) * KS * 64) return;
    int l = idx & 63;
    int s = (idx >> 6) % KS;
    int t = idx / (64 * KS);
    int k0 = s * 32 + (l >> 4) * 8;
    int n  = t * 16 + (l & 15);
    size_t base = (size_t)idx * 8;
#pragma unroll
    for (int j = 0; j < 8; ++j) {
        int k = k0 + j;
        float w = (k < Krows) ? W[(size_t)k * N + n] : 0.0f;
        unsigned short h = f2bf(w);
        float rem = w - bf2f(h);
        hi[base + j] = h;
        lo[base + j] = f2bf(rem);
    }
}

// ---------------- cast: xb[n][c] = bf16(x[n][c] * dis[n]) padded to 64 cols ----------------
__global__ __launch_bounds__(256, 4)
void cast_x_kernel(const float* __restrict__ x, const float* __restrict__ dis,
                   unsigned short* __restrict__ xb) {
    int idx = blockIdx.x * blockDim.x + threadIdx.x;
    if (idx >= N_NODES * 64) return;
    int n = idx >> 6, c = idx & 63;
    xb[idx] = (c < 37) ? f2bf(x[(size_t)n * 37 + c] * dis[n]) : (unsigned short)0;
}

// ---------------- aggregation over bf16 table (tile-phased order) ----------
template<int F>
__device__ __forceinline__ void agg_range(const unsigned short* __restrict__ tab,
                                          const int* __restrict__ csr_src,
                                          int j, int hi, int lane, float* acc) {
    for (; j + 16 <= hi; j += 16) {
        int sidx[16];
#pragma unroll
        for (int u = 0; u < 16; ++u) sidx[u] = csr_src[j + u];
        if (F == 64) {
            unsigned short v[16];
#pragma unroll
            for (int u = 0; u < 16; ++u) v[u] = tab[(size_t)sidx[u] * 64 + lane];
#pragma unroll
            for (int u = 0; u < 16; ++u) acc[0] += bf2f(v[u]);
        } else if (F == 128) {
            ushort2 v[16];
#pragma unroll
            for (int u = 0; u < 16; ++u)
                v[u] = ((const ushort2*)(tab + (size_t)sidx[u] * F))[lane];
#pragma unroll
            for (int u = 0; u < 16; ++u) { acc[0] += bf2f(v[u].x); acc[1] += bf2f(v[u].y); }
        } else {
            ushort4 v[16];
#pragma unroll
            for (int u = 0; u < 16; ++u)
                v[u] = ((const ushort4*)(tab + (size_t)sidx[u] * F))[lane];
#pragma unroll
            for (int u = 0; u < 16; ++u) {
                acc[0] += bf2f(v[u].x); acc[1] += bf2f(v[u].y);
                acc[2] += bf2f(v[u].z); acc[3] += bf2f(v[u].w);
            }
        }
    }
    for (; j + 4 <= hi; j += 4) {
        int sidx[4];
#pragma unroll
        for (int u = 0; u < 4; ++u) sidx[u] = csr_src[j + u];
        if (F == 64) {
            unsigned short v[4];
#pragma unroll
            for (int u = 0; u < 4; ++u) v[u] = tab[(size_t)sidx[u] * 64 + lane];
#pragma unroll
            for (int u = 0; u < 4; ++u) acc[0] += bf2f(v[u]);
        } else if (F == 128) {
            ushort2 v[4];
#pragma unroll
            for (int u = 0; u < 4; ++u)
                v[u] = ((const ushort2*)(tab + (size_t)sidx[u] * F))[lane];
#pragma unroll
            for (int u = 0; u < 4; ++u) { acc[0] += bf2f(v[u].x); acc[1] += bf2f(v[u].y); }
        } else {
            ushort4 v[4];
#pragma unroll
            for (int u = 0; u < 4; ++u)
                v[u] = ((const ushort4*)(tab + (size_t)sidx[u] * F))[lane];
#pragma unroll
            for (int u = 0; u < 4; ++u) {
                acc[0] += bf2f(v[u].x); acc[1] += bf2f(v[u].y);
                acc[2] += bf2f(v[u].z); acc[3] += bf2f(v[u].w);
            }
        }
    }
    for (; j < hi; ++j) {
        int s = csr_src[j];
        if (F == 64) {
            acc[0] += bf2f(tab[(size_t)s * 64 + lane]);
        } else if (F == 128) {
            ushort2 u = ((const ushort2*)(tab + (size_t)s * F))[lane];
            acc[0] += bf2f(u.x); acc[1] += bf2f(u.y);
        } else {
            ushort4 u = ((const ushort4*)(tab + (size_t)s * F))[lane];
            acc[0] += bf2f(u.x); acc[1] += bf2f(u.y); acc[2] += bf2f(u.z); acc[3] += bf2f(u.w);
        }
    }
}

// out[n] = bf16( dis[n] * (tab[n] + sum_{src->n} tab[src]) )
// Edge lists are src-tile-sorted; start position phased by blockIdx so the
// resident block cohort walks the same table slice (L2-resident window).
template<int F>
__global__ __launch_bounds__(256, 4)
void agg_bf16_kernel(const unsigned short* __restrict__ tab,
                     const int* __restrict__ csr_src,
                     const int* __restrict__ tileoff,
                     const float* __restrict__ dis,
                     unsigned short* __restrict__ out) {
    int wave = threadIdx.x >> 6;
    int lane = threadIdx.x & 63;
    int n = blockIdx.x * 4 + wave;

    float acc[(F + 63) / 64];
    if (F == 64) {
        acc[0] = bf2f(tab[(size_t)n * 64 + lane]);
    } else if (F == 128) {
        ushort2 u = ((const ushort2*)(tab + (size_t)n * F))[lane];
        acc[0] = bf2f(u.x); acc[1] = bf2f(u.y);
    } else {
        ushort4 u = ((const ushort4*)(tab + (size_t)n * F))[lane];
        acc[0] = bf2f(u.x); acc[1] = bf2f(u.y); acc[2] = bf2f(u.z); acc[3] = bf2f(u.w);
    }

    int lo = tileoff[(size_t)n * 26 + 0];
    int hi = tileoff[(size_t)n * 26 + NT];
    int deg = hi - lo;
    int jsplit = lo + (int)(((long long)deg * blockIdx.x) / gridDim.x);

    agg_range<F>(tab, csr_src, jsplit, hi, lane, acc);
    agg_range<F>(tab, csr_src, lo, jsplit, lane, acc);

    float d = dis[n];
    if (F == 64) {
        out[(size_t)n * 64 + lane] = f2bf(d * acc[0]);
    } else if (F == 128) {
        ushort2 o; o.x = f2bf(d * acc[0]); o.y = f2bf(d * acc[1]);
        ((ushort2*)(out + (size_t)n * F))[lane] = o;
    } else {
        ushort4 o;
        o.x = f2bf(d * acc[0]); o.y = f2bf(d * acc[1]);
        o.z = f2bf(d * acc[2]); o.w = f2bf(d * acc[3]);
        ((ushort4*)(out + (size_t)n * F))[lane] = o;
    }
}

// ---------------- MFMA GEMM: A bf16 [M×K] @ (Whi+Wlo) [K×N] + bias, relu ---------------
// Block: 32 rows × N cols, 4 waves; wave w owns NTW n-tiles (N = 64*NTW... N/4 cols).
// MODE 1: out bf16 = bf16(relu(acc+b) * dis[row])   (next gather table)
// MODE 2: out bf16 = bf16(relu(acc+b))
template<int K, int NTW, int N, int MODE>
__global__ __launch_bounds__(256, 4)
void mfma_gemm_kernel(const unsigned short* __restrict__ A,
                      const unsigned short* __restrict__ Bhi,
                      const unsigned short* __restrict__ Blo,
                      const float* __restrict__ bias,
                      const float* __restrict__ dis,
                      unsigned short* __restrict__ outv) {
    constexpr int KS = K / 32;
    int l   = threadIdx.x & 63;
    int wid = threadIdx.x >> 6;      // 0..3
    int n0  = wid * (NTW * 16);
    int m0  = blockIdx.x * 32;

    f32x4 acc0[NTW], acc1[NTW];
#pragma unroll
    for (int tn = 0; tn < NTW; ++tn) { acc0[tn] = (f32x4){0,0,0,0}; acc1[tn] = (f32x4){0,0,0,0}; }

    const unsigned short* a0 = A + (size_t)(m0 + (l & 15)) * K + (l >> 4) * 8;
    const unsigned short* a1 = a0 + (size_t)16 * K;

#pragma unroll
    for (int s = 0; s < KS; ++s) {
        bf16x8 af0 = *(const bf16x8*)(a0 + s * 32);
        bf16x8 af1 = *(const bf16x8*)(a1 + s * 32);
#pragma unroll
        for (int tn = 0; tn < NTW; ++tn) {
            int t = (n0 >> 4) + tn;
            size_t boff = ((size_t)(t * KS + s) * 64 + l) * 8;
            bf16x8 bh = *(const bf16x8*)(Bhi + boff);
            bf16x8 bl = *(const bf16x8*)(Blo + boff);
            acc0[tn] = __builtin_amdgcn_mfma_f32_16x16x32_bf16(af0, bh, acc0[tn], 0, 0, 0);
            acc0[tn] = __builtin_amdgcn_mfma_f32_16x16x32_bf16(af0, bl, acc0[tn], 0, 0, 0);
            acc1[tn] = __builtin_amdgcn_mfma_f32_16x16x32_bf16(af1, bh, acc1[tn], 0, 0, 0);
            acc1[tn] = __builtin_amdgcn_mfma_f32_16x16x32_bf16(af1, bl, acc1[tn], 0, 0, 0);
        }
    }

    int rowg = (l >> 4) * 4;
#pragma unroll
    for (int tn = 0; tn < NTW; ++tn) {
        int n = n0 + tn * 16 + (l & 15);
        float b = bias[n];
#pragma unroll
        for (int r = 0; r < 4; ++r) {
#pragma unroll
            for (int half = 0; half < 2; ++half) {
                int m = m0 + half * 16 + rowg + r;
                float v = fmaxf((half ? acc1[tn][r] : acc0[tn][r]) + b, 0.0f);
                if (MODE == 1) outv[(size_t)m * N + n] = f2bf(v * dis[m]);
                else           outv[(size_t)m * N + n] = f2bf(v);
            }
        }
    }
}

// ---------------- pooling (bf16 input, wave per graph) ----------------
__device__ __forceinline__ int lower_bound_dev(const int* __restrict__ a, int n, int key) {
    int lo = 0, hi = n;
    while (lo < hi) {
        int mid = (lo + hi) >> 1;
        if (a[mid] < key) lo = mid + 1; else hi = mid;
    }
    return lo;
}

__global__ __launch_bounds__(256, 4)
void pool_bf16_kernel(const unsigned short* __restrict__ h, const int* __restrict__ batch,
                      float* __restrict__ pooled) {
    int wave = threadIdx.x >> 6;
    int lane = threadIdx.x & 63;
    int g = blockIdx.x * 4 + wave;
    int lo = lower_bound_dev(batch, N_NODES, g);
    int hi = lower_bound_dev(batch, N_NODES, g + 1);
    float a0 = 0, a1 = 0, a2 = 0, a3 = 0;
    for (int n = lo; n < hi; ++n) {
        ushort4 u = ((const ushort4*)(h + (size_t)n * 256))[lane];
        a0 += bf2f(u.x); a1 += bf2f(u.y); a2 += bf2f(u.z); a3 += bf2f(u.w);
    }
    float inv = 1.0f / fmaxf((float)(hi - lo), 1.0f);
    float4 o = {a0 * inv, a1 * inv, a2 * inv, a3 * inv};
    *(float4*)&pooled[(size_t)g * 256 + lane * 4] = o;
}

// ---------------- head GEMM (fp32 naive, tiny M) ----------------
__global__ __launch_bounds__(256, 2)
void head_gemm_kernel(const float* __restrict__ H, const float* __restrict__ W,
                      const float* __restrict__ bias, float* __restrict__ out) {
    __shared__ float lds[16 * 256];
    int row0 = blockIdx.x * 16;
    int t = threadIdx.x;   // 0..255 (= col)
    const float* src = H + (size_t)row0 * 256;
    for (int i = t; i < 16 * 256; i += 256) lds[i] = src[i];
    __syncthreads();
    float acc[16];
#pragma unroll
    for (int r = 0; r < 16; ++r) acc[r] = 0.0f;
#pragma unroll 4
    for (int k = 0; k < 256; ++k) {
        float wv = W[k * 256 + t];
#pragma unroll
        for (int r = 0; r < 16; ++r) acc[r] += lds[r * 256 + k] * wv;
    }
#pragma unroll
    for (int r = 0; r < 16; ++r)
        out[(size_t)(row0 + r) * 256 + t] = acc[r] + bias[t];
}

// ---------------- launch ----------------
static inline size_t align_up(size_t x, size_t a) { return (x + a - 1) & ~(a - 1); }

extern "C" void kernel_launch(void* const* d_in, const int* in_sizes, int n_in,
                              void* d_out, int out_size, void* d_ws, size_t ws_size,
                              hipStream_t stream) {
    const float* x  = (const float*)d_in[0];
    const float* W1 = (const float*)d_in[1];
    const float* b1 = (const float*)d_in[2];
    const float* W2 = (const float*)d_in[3];
    const float* b2 = (const float*)d_in[4];
    const float* W3 = (const float*)d_in[5];
    const float* b3 = (const float*)d_in[6];
    const float* Wp = (const float*)d_in[7];
    const float* bp = (const float*)d_in[8];
    const int*   ei = (const int*)d_in[9];   // [2, E]
    const int*   batch = (const int*)d_in[10];
    float* out = (float*)d_out;

    const int* e_src = ei;
    const int* e_dst = ei + N_EDGES;

    char* p = (char*)d_ws;
    size_t off = 0;
    auto take = [&](size_t bytes) {
        void* r = p + off;
        off = align_up(off + bytes, 256);
        return r;
    };
    int*   hist        = (int*)  take(sizeof(int) * NB * NBLK);
    int*   tot         = (int*)  take(sizeof(int) * NB);
    int*   bucketStart = (int*)  take(sizeof(int) * (NB + 1));
    int*   tileoff     = (int*)  take(sizeof(int) * (size_t)N_NODES * 26);
    int*   csr_src     = (int*)  take(sizeof(int) * N_EDGES);
    float* dis         = (float*)take(sizeof(float) * N_NODES);
    float* pooled      = (float*)take(sizeof(float) * N_GRAPHS * 256);
    unsigned short* whi1 = (unsigned short*)take(sizeof(unsigned short) * 64 * 128);
    unsigned short* wlo1 = (unsigned short*)take(sizeof(unsigned short) * 64 * 128);
    unsigned short* whi2 = (unsigned short*)take(sizeof(unsigned short) * 128 * 256);
    unsigned short* wlo2 = (unsigned short*)take(sizeof(unsigned short) * 128 * 256);
    unsigned short* whi3 = (unsigned short*)take(sizeof(unsigned short) * 256 * 256);
    unsigned short* wlo3 = (unsigned short*)take(sizeof(unsigned short) * 256 * 256);
    unsigned short* bufX = (unsigned short*)take(sizeof(unsigned short) * (size_t)N_NODES * 256);
    unsigned short* bufY = (unsigned short*)take(sizeof(unsigned short) * (size_t)N_NODES * 256);
    unsigned short* h3   = (unsigned short*)take(sizeof(unsigned short) * (size_t)N_NODES * 256);

    // CSR-build scratch aliases h3 (consumed before h3 is written): 2*E ints = 25.6 MB <= 51.2 MB
    int* sdst = (int*)h3;
    int* ssrc = sdst + N_EDGES;

    // buffer plan (bufX/bufY halves, 25.6 MB each):
    unsigned short* xb     = bufY;                               // [100K×64]
    unsigned short* pbuf1  = bufY + (size_t)N_NODES * 64;        // [100K×64]
    unsigned short* table2 = bufX;                               // [100K×128]
    unsigned short* pbuf2  = bufX + (size_t)N_NODES * 128;       // [100K×128]
    unsigned short* table3 = bufY;                               // [100K×256] (xb/pbuf1 dead)
    unsigned short* pbuf3  = bufX;                               // [100K×256] (table2/pbuf2 dead)

    // ---- CSR build via counting sort (no global atomics), src-tile-sorted lists ----
    hist_kernel<<<NBLK, 256, 0, stream>>>(e_dst, hist);
    bucket_tot_kernel<<<NB, 64, 0, stream>>>(hist, tot);
    bucket_scan_kernel<<<1, 256, 0, stream>>>(tot, bucketStart);
    bucket_base_kernel<<<(NB + 255) / 256, 256, 0, stream>>>(hist, bucketStart);
    scatter1_kernel<<<NBLK, 256, 0, stream>>>(e_src, e_dst, hist, sdst, ssrc);
    csr2_kernel<<<NB, 256, 0, stream>>>(sdst, ssrc, bucketStart, tileoff, dis, csr_src);

    // pack weights into MFMA B-frag split-bf16 planes
    pack_w_kernel<64, 128><<<((128 / 16) * 2 * 64 + 255) / 256, 256, 0, stream>>>(W1, 37, whi1, wlo1);
    pack_w_kernel<128, 256><<<((256 / 16) * 4 * 64 + 255) / 256, 256, 0, stream>>>(W2, 128, whi2, wlo2);
    pack_w_kernel<256, 256><<<((256 / 16) * 8 * 64 + 255) / 256, 256, 0, stream>>>(W3, 256, whi3, wlo3);

    // Layer 1 (input-dim gather): xb = bf16(x*dis) pad64; pbuf1 = bf16(dis*agg(xb));
    // table2 = bf16(relu(pbuf1@W1 + b1) * dis)
    cast_x_kernel<<<(N_NODES * 64 + 255) / 256, 256, 0, stream>>>(x, dis, xb);
    agg_bf16_kernel<64><<<N_NODES / 4, 256, 0, stream>>>(xb, csr_src, tileoff, dis, pbuf1);
    mfma_gemm_kernel<64, 2, 128, 1><<<N_NODES / 32, 256, 0, stream>>>(pbuf1, whi1, wlo1, b1, dis, table2);

    // Layer 2 (propagate-first)
    agg_bf16_kernel<128><<<N_NODES / 4, 256, 0, stream>>>(table2, csr_src, tileoff, dis, pbuf2);
    mfma_gemm_kernel<128, 4, 256, 1><<<N_NODES / 32, 256, 0, stream>>>(pbuf2, whi2, wlo2, b2, dis, table3);

    // Layer 3 (propagate-first): h3 bf16
    agg_bf16_kernel<256><<<N_NODES / 4, 256, 0, stream>>>(table3, csr_src, tileoff, dis, pbuf3);
    mfma_gemm_kernel<256, 4, 256, 2><<<N_NODES / 32, 256, 0, stream>>>(pbuf3, whi3, wlo3, b3, nullptr, h3);

    // pool + head
    pool_bf16_kernel<<<N_GRAPHS / 4, 256, 0, stream>>>(h3, batch, pooled);
    head_gemm_kernel<<<N_GRAPHS / 16, 256, 0, stream>>>(pooled, Wp, bp, out);
}

// Round 8
// 661.847 us; speedup vs baseline: 1.1179x; 1.1179x over previous
//
#include <hip/hip_runtime.h>

#define N_NODES  100000
#define N_EDGES  3200000
#define N_GRAPHS 3200

// CSR-build constants
#define NBLK 200            // edge-chunk blocks
#define EB   16000          // edges per chunk (NBLK*EB == N_EDGES)
#define BSH  7              // bucket = dst >> 7  (128 nodes/bucket)
#define NB   ((N_NODES + 127) >> BSH)   // 782 buckets
#define BCAP 5120           // max edges per bucket staged in LDS

typedef __attribute__((ext_vector_type(8))) short bf16x8;
typedef __attribute__((ext_vector_type(4))) float f32x4;

// ---------------- bf16 helpers ----------------
__device__ __forceinline__ float bf2f(unsigned short u) {
    return __uint_as_float(((unsigned)u) << 16);
}
__device__ __forceinline__ unsigned short f2bf(float f) {
    unsigned u = __float_as_uint(f);
    u += 0x7fffu + ((u >> 16) & 1u);   // RNE
    return (unsigned short)(u >> 16);
}

// ================= CSR build (counting sort, no global atomics) =================

__global__ __launch_bounds__(256, 4)
void hist_kernel(const int* __restrict__ dst, int* __restrict__ hist) {
    __shared__ int lh[NB];
    int blk = blockIdx.x, t = threadIdx.x;
    for (int b = t; b < NB; b += 256) lh[b] = 0;
    __syncthreads();
    int e0 = blk * EB;
    for (int i = t; i < EB; i += 256)
        atomicAdd(&lh[dst[e0 + i] >> BSH], 1);
    __syncthreads();
    for (int b = t; b < NB; b += 256) hist[b * NBLK + blk] = lh[b];
}

__global__ void bucket_tot_kernel(const int* __restrict__ hist, int* __restrict__ tot) {
    int b = blockIdx.x, l = threadIdx.x;   // 64 threads
    int s = 0;
    for (int k = l; k < NBLK; k += 64) s += hist[b * NBLK + k];
    for (int off = 32; off; off >>= 1) s += __shfl_down(s, off);
    if (l == 0) tot[b] = s;
}

__global__ void bucket_scan_kernel(const int* __restrict__ tot, int* __restrict__ bucketStart) {
    __shared__ int part[256];
    int t = threadIdx.x;
    int chunk = (NB + 255) / 256;
    int lo = t * chunk; if (lo > NB) lo = NB;
    int hi = lo + chunk; if (hi > NB) hi = NB;
    int s = 0;
    for (int i = lo; i < hi; ++i) s += tot[i];
    part[t] = s;
    __syncthreads();
    for (int off = 1; off < 256; off <<= 1) {
        int v = part[t];
        int a = (t >= off) ? part[t - off] : 0;
        __syncthreads();
        part[t] = v + a;
        __syncthreads();
    }
    int run = (t == 0) ? 0 : part[t - 1];
    for (int i = lo; i < hi; ++i) { bucketStart[i] = run; run += tot[i]; }
    if (t == 255) bucketStart[NB] = run;
}

__global__ void bucket_base_kernel(int* __restrict__ hist, const int* __restrict__ bucketStart) {
    int b = blockIdx.x * blockDim.x + threadIdx.x;
    if (b >= NB) return;
    int run = bucketStart[b];
    int* row = hist + b * NBLK;
#pragma unroll 4
    for (int k = 0; k < NBLK; ++k) { int v = row[k]; row[k] = run; run += v; }
}

__global__ __launch_bounds__(256, 4)
void scatter1_kernel(const int* __restrict__ src, const int* __restrict__ dst,
                     const int* __restrict__ base,
                     int* __restrict__ sdst, int* __restrict__ ssrc) {
    __shared__ int lcur[NB];
    int blk = blockIdx.x, t = threadIdx.x;
    for (int b = t; b < NB; b += 256) lcur[b] = base[b * NBLK + blk];
    __syncthreads();
    int e0 = blk * EB;
    for (int i = t; i < EB; i += 256) {
        int d = dst[e0 + i], s = src[e0 + i];
        int pos = atomicAdd(&lcur[d >> BSH], 1);
        sdst[pos] = d;
        ssrc[pos] = s;
    }
}

__global__ __launch_bounds__(256, 1)
void csr2_kernel(const int* __restrict__ sdst, const int* __restrict__ ssrc,
                 const int* __restrict__ bucketStart,
                 int* __restrict__ offsets, float* __restrict__ dis,
                 int* __restrict__ csr_src) {
    __shared__ int ldst[BCAP];
    __shared__ int lsrc[BCAP];
    __shared__ int lhist[128], loff[128], lcur[128];
    int b = blockIdx.x, t = threadIdx.x;
    int n0 = b << BSH;
    int e0 = bucketStart[b], e1 = bucketStart[b + 1];
    int cnt = e1 - e0; if (cnt > BCAP) cnt = BCAP;
    for (int i = t; i < cnt; i += 256) {
        ldst[i] = sdst[e0 + i] - n0;   // 0..127
        lsrc[i] = ssrc[e0 + i];
    }
    if (t < 128) lhist[t] = 0;
    __syncthreads();
    for (int i = t; i < cnt; i += 256) atomicAdd(&lhist[ldst[i]], 1);
    __syncthreads();
    if (t < 128) loff[t] = lhist[t];
    __syncthreads();
    for (int off = 1; off < 128; off <<= 1) {   // Hillis-Steele inclusive scan
        int v = 0;
        if (t < 128) { v = loff[t]; if (t >= off) v += loff[t - off]; }
        __syncthreads();
        if (t < 128) loff[t] = v;
        __syncthreads();
    }
    if (t < 128) {
        int excl = loff[t] - lhist[t];
        lcur[t] = excl;
        int n = n0 + t;
        if (n < N_NODES) {
            offsets[n] = e0 + excl;
            dis[n] = rsqrtf((float)lhist[t] + 1.0f);
        }
    }
    if (b == 0 && t == 0) offsets[N_NODES] = N_EDGES;
    __syncthreads();
    for (int i = t; i < cnt; i += 256) {
        int pos = atomicAdd(&lcur[ldst[i]], 1);
        csr_src[e0 + pos] = lsrc[i];
    }
}

// ---------------- pack W[Krows x N] fp32 -> split bf16 planes in MFMA B-frag layout --------
template<int K, int N>
__global__ void pack_w_kernel(const float* __restrict__ W, int Krows,
                              unsigned short* __restrict__ hi,
                              unsigned short* __restrict__ lo) {
    constexpr int KS = K / 32;
    int idx = blockIdx.x * blockDim.x + threadIdx.x;
    if (idx >= (N / 16) * KS * 64) return;
    int l = idx & 63;
    int s = (idx >> 6) % KS;
    int t = idx / (64 * KS);
    int k0 = s * 32 + (l >> 4) * 8;
    int n  = t * 16 + (l & 15);
    size_t base = (size_t)idx * 8;
#pragma unroll
    for (int j = 0; j < 8; ++j) {
        int k = k0 + j;
        float w = (k < Krows) ? W[(size_t)k * N + n] : 0.0f;
        unsigned short h = f2bf(w);
        float rem = w - bf2f(h);
        hi[base + j] = h;
        lo[base + j] = f2bf(rem);
    }
}

// ---------------- cast: xb[n][c] = bf16(x[n][c] * dis[n]) padded to 64 cols ----------------
__global__ __launch_bounds__(256, 4)
void cast_x_kernel(const float* __restrict__ x, const float* __restrict__ dis,
                   unsigned short* __restrict__ xb) {
    int idx = blockIdx.x * blockDim.x + threadIdx.x;
    if (idx >= N_NODES * 64) return;
    int n = idx >> 6, c = idx & 63;
    xb[idx] = (c < 37) ? f2bf(x[(size_t)n * 37 + c] * dis[n]) : (unsigned short)0;
}

// ---------------- per-node gather-sum (16/4/1-deep MLP), R6-proven ----------
template<int F>
__device__ __forceinline__ void agg_range(const unsigned short* __restrict__ tab,
                                          const int* __restrict__ csr_src,
                                          int j, int hi, int lane, float* acc) {
    for (; j + 16 <= hi; j += 16) {
        int sidx[16];
#pragma unroll
        for (int u = 0; u < 16; ++u) sidx[u] = csr_src[j + u];
        if (F == 64) {
            unsigned short v[16];
#pragma unroll
            for (int u = 0; u < 16; ++u) v[u] = tab[(size_t)sidx[u] * 64 + lane];
#pragma unroll
            for (int u = 0; u < 16; ++u) acc[0] += bf2f(v[u]);
        } else if (F == 128) {
            ushort2 v[16];
#pragma unroll
            for (int u = 0; u < 16; ++u)
                v[u] = ((const ushort2*)(tab + (size_t)sidx[u] * F))[lane];
#pragma unroll
            for (int u = 0; u < 16; ++u) { acc[0] += bf2f(v[u].x); acc[1] += bf2f(v[u].y); }
        } else {
            ushort4 v[16];
#pragma unroll
            for (int u = 0; u < 16; ++u)
                v[u] = ((const ushort4*)(tab + (size_t)sidx[u] * F))[lane];
#pragma unroll
            for (int u = 0; u < 16; ++u) {
                acc[0] += bf2f(v[u].x); acc[1] += bf2f(v[u].y);
                acc[2] += bf2f(v[u].z); acc[3] += bf2f(v[u].w);
            }
        }
    }
    for (; j + 4 <= hi; j += 4) {
        int sidx[4];
#pragma unroll
        for (int u = 0; u < 4; ++u) sidx[u] = csr_src[j + u];
        if (F == 64) {
            unsigned short v[4];
#pragma unroll
            for (int u = 0; u < 4; ++u) v[u] = tab[(size_t)sidx[u] * 64 + lane];
#pragma unroll
            for (int u = 0; u < 4; ++u) acc[0] += bf2f(v[u]);
        } else if (F == 128) {
            ushort2 v[4];
#pragma unroll
            for (int u = 0; u < 4; ++u)
                v[u] = ((const ushort2*)(tab + (size_t)sidx[u] * F))[lane];
#pragma unroll
            for (int u = 0; u < 4; ++u) { acc[0] += bf2f(v[u].x); acc[1] += bf2f(v[u].y); }
        } else {
            ushort4 v[4];
#pragma unroll
            for (int u = 0; u < 4; ++u)
                v[u] = ((const ushort4*)(tab + (size_t)sidx[u] * F))[lane];
#pragma unroll
            for (int u = 0; u < 4; ++u) {
                acc[0] += bf2f(v[u].x); acc[1] += bf2f(v[u].y);
                acc[2] += bf2f(v[u].z); acc[3] += bf2f(v[u].w);
            }
        }
    }
    for (; j < hi; ++j) {
        int s = csr_src[j];
        if (F == 64) {
            acc[0] += bf2f(tab[(size_t)s * 64 + lane]);
        } else if (F == 128) {
            ushort2 u = ((const ushort2*)(tab + (size_t)s * F))[lane];
            acc[0] += bf2f(u.x); acc[1] += bf2f(u.y);
        } else {
            ushort4 u = ((const ushort4*)(tab + (size_t)s * F))[lane];
            acc[0] += bf2f(u.x); acc[1] += bf2f(u.y); acc[2] += bf2f(u.z); acc[3] += bf2f(u.w);
        }
    }
}

// ---------------- FUSED: agg (K-wide) -> LDS A-tile -> MFMA @ (Whi+Wlo)[K×N] + bias, relu
// Block = 32 output rows, 4 waves. Phase A: wave w aggregates rows w*8..w*8+7:
// A[r] = bf16( dis[n] * (tab[n] + sum_{src->n} tab[src]) ), stored XOR-swizzled in LDS.
// Phase B: standard MFMA (A-frag row=l&15(+16), k=(l>>4)*8+8j) read from swizzled LDS.
// MODE 1: out = bf16(relu(acc+b)*dis[m]) (next gather table); MODE 2: out = bf16(relu(acc+b))
template<int K, int NTW, int N, int MODE>
__global__ __launch_bounds__(256, 4)
void fused_agg_gemm(const unsigned short* __restrict__ tab,
                    const int* __restrict__ csr_src,
                    const int* __restrict__ offsets,
                    const float* __restrict__ dis,
                    const unsigned short* __restrict__ Bhi,
                    const unsigned short* __restrict__ Blo,
                    const float* __restrict__ bias,
                    unsigned short* __restrict__ out) {
    constexpr int KS = K / 32;
    __shared__ unsigned short ldsA[32 * K];
    char* lb = (char*)ldsA;
    int l = threadIdx.x & 63;
    int w = threadIdx.x >> 6;      // 0..3
    int m0 = blockIdx.x * 32;

    // ---- Phase A: aggregate 8 nodes per wave ----
    for (int i = 0; i < 8; ++i) {
        int r = w * 8 + i;
        int n = m0 + r;
        float acc[(K + 63) / 64];
        if (K == 64) {
            acc[0] = bf2f(tab[(size_t)n * 64 + l]);
        } else if (K == 128) {
            ushort2 u = ((const ushort2*)(tab + (size_t)n * K))[l];
            acc[0] = bf2f(u.x); acc[1] = bf2f(u.y);
        } else {
            ushort4 u = ((const ushort4*)(tab + (size_t)n * K))[l];
            acc[0] = bf2f(u.x); acc[1] = bf2f(u.y); acc[2] = bf2f(u.z); acc[3] = bf2f(u.w);
        }
        agg_range<K>(tab, csr_src, offsets[n], offsets[n + 1], l, acc);
        float d = dis[n];
        unsigned sw = (unsigned)((r & 7) << 4);
        if (K == 64) {
            *(unsigned short*)(lb + ((unsigned)(r * 128 + l * 2) ^ sw)) = f2bf(d * acc[0]);
        } else if (K == 128) {
            ushort2 o; o.x = f2bf(d * acc[0]); o.y = f2bf(d * acc[1]);
            *(ushort2*)(lb + ((unsigned)(r * 256 + l * 4) ^ sw)) = o;
        } else {
            ushort4 o;
            o.x = f2bf(d * acc[0]); o.y = f2bf(d * acc[1]);
            o.z = f2bf(d * acc[2]); o.w = f2bf(d * acc[3]);
            *(ushort4*)(lb + ((unsigned)(r * 512 + l * 8) ^ sw)) = o;
        }
    }
    __syncthreads();

    // ---- Phase B: MFMA from LDS A ----
    int n0 = w * (NTW * 16);
    f32x4 acc0[NTW], acc1[NTW];
#pragma unroll
    for (int tn = 0; tn < NTW; ++tn) { acc0[tn] = (f32x4){0,0,0,0}; acc1[tn] = (f32x4){0,0,0,0}; }

    int r0 = l & 15, r1 = r0 + 16;
    unsigned sw0 = (unsigned)((r0 & 7) << 4);
#pragma unroll
    for (int s = 0; s < KS; ++s) {
        unsigned kb = (unsigned)(s * 64 + (l >> 4) * 16);
        bf16x8 af0 = *(const bf16x8*)(lb + ((unsigned)(r0 * K * 2 + kb) ^ sw0));
        bf16x8 af1 = *(const bf16x8*)(lb + ((unsigned)(r1 * K * 2 + kb) ^ sw0));
#pragma unroll
        for (int tn = 0; tn < NTW; ++tn) {
            int t = (n0 >> 4) + tn;
            size_t boff = ((size_t)(t * KS + s) * 64 + l) * 8;
            bf16x8 bh = *(const bf16x8*)(Bhi + boff);
            bf16x8 bl = *(const bf16x8*)(Blo + boff);
            acc0[tn] = __builtin_amdgcn_mfma_f32_16x16x32_bf16(af0, bh, acc0[tn], 0, 0, 0);
            acc0[tn] = __builtin_amdgcn_mfma_f32_16x16x32_bf16(af0, bl, acc0[tn], 0, 0, 0);
            acc1[tn] = __builtin_amdgcn_mfma_f32_16x16x32_bf16(af1, bh, acc1[tn], 0, 0, 0);
            acc1[tn] = __builtin_amdgcn_mfma_f32_16x16x32_bf16(af1, bl, acc1[tn], 0, 0, 0);
        }
    }

    int rowg = (l >> 4) * 4;
#pragma unroll
    for (int tn = 0; tn < NTW; ++tn) {
        int n = n0 + tn * 16 + (l & 15);
        float b = bias[n];
#pragma unroll
        for (int r = 0; r < 4; ++r) {
#pragma unroll
            for (int half = 0; half < 2; ++half) {
                int m = m0 + half * 16 + rowg + r;
                float v = fmaxf((half ? acc1[tn][r] : acc0[tn][r]) + b, 0.0f);
                if (MODE == 1) out[(size_t)m * N + n] = f2bf(v * dis[m]);
                else           out[(size_t)m * N + n] = f2bf(v);
            }
        }
    }
}

// ---------------- pooling (bf16 input, wave per graph) ----------------
__device__ __forceinline__ int lower_bound_dev(const int* __restrict__ a, int n, int key) {
    int lo = 0, hi = n;
    while (lo < hi) {
        int mid = (lo + hi) >> 1;
        if (a[mid] < key) lo = mid + 1; else hi = mid;
    }
    return lo;
}

__global__ __launch_bounds__(256, 4)
void pool_bf16_kernel(const unsigned short* __restrict__ h, const int* __restrict__ batch,
                      float* __restrict__ pooled) {
    int wave = threadIdx.x >> 6;
    int lane = threadIdx.x & 63;
    int g = blockIdx.x * 4 + wave;
    int lo = lower_bound_dev(batch, N_NODES, g);
    int hi = lower_bound_dev(batch, N_NODES, g + 1);
    float a0 = 0, a1 = 0, a2 = 0, a3 = 0;
    for (int n = lo; n < hi; ++n) {
        ushort4 u = ((const ushort4*)(h + (size_t)n * 256))[lane];
        a0 += bf2f(u.x); a1 += bf2f(u.y); a2 += bf2f(u.z); a3 += bf2f(u.w);
    }
    float inv = 1.0f / fmaxf((float)(hi - lo), 1.0f);
    float4 o = {a0 * inv, a1 * inv, a2 * inv, a3 * inv};
    *(float4*)&pooled[(size_t)g * 256 + lane * 4] = o;
}

// ---------------- head GEMM (fp32 naive, tiny M) ----------------
__global__ __launch_bounds__(256, 2)
void head_gemm_kernel(const float* __restrict__ H, const float* __restrict__ W,
                      const float* __restrict__ bias, float* __restrict__ out) {
    __shared__ float lds[16 * 256];
    int row0 = blockIdx.x * 16;
    int t = threadIdx.x;   // 0..255 (= col)
    const float* src = H + (size_t)row0 * 256;
    for (int i = t; i < 16 * 256; i += 256) lds[i] = src[i];
    __syncthreads();
    float acc[16];
#pragma unroll
    for (int r = 0; r < 16; ++r) acc[r] = 0.0f;
#pragma unroll 4
    for (int k = 0; k < 256; ++k) {
        float wv = W[k * 256 + t];
#pragma unroll
        for (int r = 0; r < 16; ++r) acc[r] += lds[r * 256 + k] * wv;
    }
#pragma unroll
    for (int r = 0; r < 16; ++r)
        out[(size_t)(row0 + r) * 256 + t] = acc[r] + bias[t];
}

// ---------------- launch ----------------
static inline size_t align_up(size_t x, size_t a) { return (x + a - 1) & ~(a - 1); }

extern "C" void kernel_launch(void* const* d_in, const int* in_sizes, int n_in,
                              void* d_out, int out_size, void* d_ws, size_t ws_size,
                              hipStream_t stream) {
    const float* x  = (const float*)d_in[0];
    const float* W1 = (const float*)d_in[1];
    const float* b1 = (const float*)d_in[2];
    const float* W2 = (const float*)d_in[3];
    const float* b2 = (const float*)d_in[4];
    const float* W3 = (const float*)d_in[5];
    const float* b3 = (const float*)d_in[6];
    const float* Wp = (const float*)d_in[7];
    const float* bp = (const float*)d_in[8];
    const int*   ei = (const int*)d_in[9];   // [2, E]
    const int*   batch = (const int*)d_in[10];
    float* out = (float*)d_out;

    const int* e_src = ei;
    const int* e_dst = ei + N_EDGES;

    char* p = (char*)d_ws;
    size_t off = 0;
    auto take = [&](size_t bytes) {
        void* r = p + off;
        off = align_up(off + bytes, 256);
        return r;
    };
    int*   hist        = (int*)  take(sizeof(int) * NB * NBLK);
    int*   tot         = (int*)  take(sizeof(int) * NB);
    int*   bucketStart = (int*)  take(sizeof(int) * (NB + 1));
    int*   offsets     = (int*)  take(sizeof(int) * (N_NODES + 1));
    int*   csr_src     = (int*)  take(sizeof(int) * N_EDGES);
    float* dis         = (float*)take(sizeof(float) * N_NODES);
    float* pooled      = (float*)take(sizeof(float) * N_GRAPHS * 256);
    unsigned short* whi1 = (unsigned short*)take(sizeof(unsigned short) * 64 * 128);
    unsigned short* wlo1 = (unsigned short*)take(sizeof(unsigned short) * 64 * 128);
    unsigned short* whi2 = (unsigned short*)take(sizeof(unsigned short) * 128 * 256);
    unsigned short* wlo2 = (unsigned short*)take(sizeof(unsigned short) * 128 * 256);
    unsigned short* whi3 = (unsigned short*)take(sizeof(unsigned short) * 256 * 256);
    unsigned short* wlo3 = (unsigned short*)take(sizeof(unsigned short) * 256 * 256);
    unsigned short* bufX = (unsigned short*)take(sizeof(unsigned short) * (size_t)N_NODES * 256);
    unsigned short* bufY = (unsigned short*)take(sizeof(unsigned short) * (size_t)N_NODES * 256);
    unsigned short* h3   = (unsigned short*)take(sizeof(unsigned short) * (size_t)N_NODES * 256);

    // CSR-build scratch aliases h3 (consumed in csr2 before h3 is written)
    int* sdst = (int*)h3;
    int* ssrc = sdst + N_EDGES;

    // table plan: xb [100K×64] in bufY; table2 [100K×128] in bufX;
    // table3 [100K×256] in bufY (xb dead); h3 separate.
    unsigned short* xb     = bufY;
    unsigned short* table2 = bufX;
    unsigned short* table3 = bufY;

    // ---- CSR build via counting sort (no global atomics) ----
    hist_kernel<<<NBLK, 256, 0, stream>>>(e_dst, hist);
    bucket_tot_kernel<<<NB, 64, 0, stream>>>(hist, tot);
    bucket_scan_kernel<<<1, 256, 0, stream>>>(tot, bucketStart);
    bucket_base_kernel<<<(NB + 255) / 256, 256, 0, stream>>>(hist, bucketStart);
    scatter1_kernel<<<NBLK, 256, 0, stream>>>(e_src, e_dst, hist, sdst, ssrc);
    csr2_kernel<<<NB, 256, 0, stream>>>(sdst, ssrc, bucketStart, offsets, dis, csr_src);

    // pack weights into MFMA B-frag split-bf16 planes
    pack_w_kernel<64, 128><<<((128 / 16) * 2 * 64 + 255) / 256, 256, 0, stream>>>(W1, 37, whi1, wlo1);
    pack_w_kernel<128, 256><<<((256 / 16) * 4 * 64 + 255) / 256, 256, 0, stream>>>(W2, 128, whi2, wlo2);
    pack_w_kernel<256, 256><<<((256 / 16) * 8 * 64 + 255) / 256, 256, 0, stream>>>(W3, 256, whi3, wlo3);

    // Layer 1: xb = bf16(x*dis) pad64; table2 = bf16(relu(agg(xb)@W1 + b1) * dis)
    cast_x_kernel<<<(N_NODES * 64 + 255) / 256, 256, 0, stream>>>(x, dis, xb);
    fused_agg_gemm<64, 2, 128, 1><<<N_NODES / 32, 256, 0, stream>>>(
        xb, csr_src, offsets, dis, whi1, wlo1, b1, table2);

    // Layer 2: table3 = bf16(relu(agg(table2)@W2 + b2) * dis)
    fused_agg_gemm<128, 4, 256, 1><<<N_NODES / 32, 256, 0, stream>>>(
        table2, csr_src, offsets, dis, whi2, wlo2, b2, table3);

    // Layer 3: h3 = bf16(relu(agg(table3)@W3 + b3))
    fused_agg_gemm<256, 4, 256, 2><<<N_NODES / 32, 256, 0, stream>>>(
        table3, csr_src, offsets, dis, whi3, wlo3, b3, h3);

    // pool + head
    pool_bf16_kernel<<<N_GRAPHS / 4, 256, 0, stream>>>(h3, batch, pooled);
    head_gemm_kernel<<<N_GRAPHS / 16, 256, 0, stream>>>(pooled, Wp, bp, out);
}

// Round 9
// 624.691 us; speedup vs baseline: 1.1844x; 1.0595x over previous
//
#include <hip/hip_runtime.h>

#define N_NODES  100000
#define N_EDGES  3200000
#define N_GRAPHS 3200

// CSR-build constants
#define NBLK 200            // edge-chunk blocks
#define EB   16000          // edges per chunk (NBLK*EB == N_EDGES)
#define BSH  7              // bucket = dst >> 7  (128 nodes/bucket)
#define NB   ((N_NODES + 127) >> BSH)   // 782 buckets
#define BCAP 5120           // max edges per bucket staged in LDS

typedef __attribute__((ext_vector_type(8))) short bf16x8;
typedef __attribute__((ext_vector_type(4))) float f32x4;

// ---------------- bf16 helpers ----------------
__device__ __forceinline__ float bf2f(unsigned short u) {
    return __uint_as_float(((unsigned)u) << 16);
}
__device__ __forceinline__ unsigned short f2bf(float f) {
    unsigned u = __float_as_uint(f);
    u += 0x7fffu + ((u >> 16) & 1u);   // RNE
    return (unsigned short)(u >> 16);
}

// ================= CSR build (counting sort, no global atomics) =================
// Edge payload packed in ONE int: (dst&127) << 17 | src   (src < 2^17)

__global__ __launch_bounds__(256, 4)
void hist_kernel(const int* __restrict__ dst, int* __restrict__ hist) {
    __shared__ int lh[NB];
    int blk = blockIdx.x, t = threadIdx.x;
    for (int b = t; b < NB; b += 256) lh[b] = 0;
    __syncthreads();
    int e0 = blk * EB;
    for (int i = t; i < EB; i += 256)
        atomicAdd(&lh[dst[e0 + i] >> BSH], 1);
    __syncthreads();
    for (int b = t; b < NB; b += 256) hist[b * NBLK + blk] = lh[b];
}

__global__ void bucket_tot_kernel(const int* __restrict__ hist, int* __restrict__ tot) {
    int b = blockIdx.x, l = threadIdx.x;   // 64 threads
    int s = 0;
    for (int k = l; k < NBLK; k += 64) s += hist[b * NBLK + k];
    for (int off = 32; off; off >>= 1) s += __shfl_down(s, off);
    if (l == 0) tot[b] = s;
}

__global__ void bucket_scan_kernel(const int* __restrict__ tot, int* __restrict__ bucketStart) {
    __shared__ int part[256];
    int t = threadIdx.x;
    int chunk = (NB + 255) / 256;
    int lo = t * chunk; if (lo > NB) lo = NB;
    int hi = lo + chunk; if (hi > NB) hi = NB;
    int s = 0;
    for (int i = lo; i < hi; ++i) s += tot[i];
    part[t] = s;
    __syncthreads();
    for (int off = 1; off < 256; off <<= 1) {
        int v = part[t];
        int a = (t >= off) ? part[t - off] : 0;
        __syncthreads();
        part[t] = v + a;
        __syncthreads();
    }
    int run = (t == 0) ? 0 : part[t - 1];
    for (int i = lo; i < hi; ++i) { bucketStart[i] = run; run += tot[i]; }
    if (t == 255) bucketStart[NB] = run;
}

__global__ void bucket_base_kernel(int* __restrict__ hist, const int* __restrict__ bucketStart) {
    int b = blockIdx.x * blockDim.x + threadIdx.x;
    if (b >= NB) return;
    int run = bucketStart[b];
    int* row = hist + b * NBLK;
#pragma unroll 4
    for (int k = 0; k < NBLK; ++k) { int v = row[k]; row[k] = run; run += v; }
}

__global__ __launch_bounds__(256, 4)
void scatter1_kernel(const int* __restrict__ src, const int* __restrict__ dst,
                     const int* __restrict__ base, int* __restrict__ spk) {
    __shared__ int lcur[NB];
    int blk = blockIdx.x, t = threadIdx.x;
    for (int b = t; b < NB; b += 256) lcur[b] = base[b * NBLK + blk];
    __syncthreads();
    int e0 = blk * EB;
    for (int i = t; i < EB; i += 256) {
        int d = dst[e0 + i], s = src[e0 + i];
        int pos = atomicAdd(&lcur[d >> BSH], 1);
        spk[pos] = ((d & 127) << 17) | s;
    }
}

__global__ __launch_bounds__(256, 1)
void csr2_kernel(const int* __restrict__ spk,
                 const int* __restrict__ bucketStart,
                 int* __restrict__ offsets, float* __restrict__ dis,
                 int* __restrict__ csr_src) {
    __shared__ int lpk[BCAP];
    __shared__ int lhist[128], loff[128], lcur[128];
    int b = blockIdx.x, t = threadIdx.x;
    int n0 = b << BSH;
    int e0 = bucketStart[b], e1 = bucketStart[b + 1];
    int cnt = e1 - e0; if (cnt > BCAP) cnt = BCAP;
    for (int i = t; i < cnt; i += 256) lpk[i] = spk[e0 + i];
    if (t < 128) lhist[t] = 0;
    __syncthreads();
    for (int i = t; i < cnt; i += 256) atomicAdd(&lhist[lpk[i] >> 17], 1);
    __syncthreads();
    if (t < 128) loff[t] = lhist[t];
    __syncthreads();
    for (int off = 1; off < 128; off <<= 1) {   // Hillis-Steele inclusive scan
        int v = 0;
        if (t < 128) { v = loff[t]; if (t >= off) v += loff[t - off]; }
        __syncthreads();
        if (t < 128) loff[t] = v;
        __syncthreads();
    }
    if (t < 128) {
        int excl = loff[t] - lhist[t];
        lcur[t] = excl;
        int n = n0 + t;
        if (n < N_NODES) {
            offsets[n] = e0 + excl;
            dis[n] = rsqrtf((float)lhist[t] + 1.0f);
        }
    }
    if (b == 0 && t == 0) offsets[N_NODES] = N_EDGES;
    __syncthreads();
    for (int i = t; i < cnt; i += 256) {
        int v = lpk[i];
        int pos = atomicAdd(&lcur[v >> 17], 1);
        csr_src[e0 + pos] = v & 0x1FFFF;
    }
}

// ---------------- pack W[Krows x N] fp32 -> split bf16 planes in MFMA B-frag layout --------
template<int K, int N>
__global__ void pack_w_kernel(const float* __restrict__ W, int Krows,
                              unsigned short* __restrict__ hi,
                              unsigned short* __restrict__ lo) {
    constexpr int KS = K / 32;
    int idx = blockIdx.x * blockDim.x + threadIdx.x;
    if (idx >= (N / 16) * KS * 64) return;
    int l = idx & 63;
    int s = (idx >> 6) % KS;
    int t = idx / (64 * KS);
    int k0 = s * 32 + (l >> 4) * 8;
    int n  = t * 16 + (l & 15);
    size_t base = (size_t)idx * 8;
#pragma unroll
    for (int j = 0; j < 8; ++j) {
        int k = k0 + j;
        float w = (k < Krows) ? W[(size_t)k * N + n] : 0.0f;
        unsigned short h = f2bf(w);
        float rem = w - bf2f(h);
        hi[base + j] = h;
        lo[base + j] = f2bf(rem);
    }
}

// ---------------- cast: xb[n][c] = bf16(x[n][c] * dis[n]) padded to 64 cols ----------------
__global__ __launch_bounds__(256, 4)
void cast_x_kernel(const float* __restrict__ x, const float* __restrict__ dis,
                   unsigned short* __restrict__ xb) {
    int idx = blockIdx.x * blockDim.x + threadIdx.x;
    if (idx >= N_NODES * 64) return;
    int n = idx >> 6, c = idx & 63;
    xb[idx] = (c < 37) ? f2bf(x[(size_t)n * 37 + c] * dis[n]) : (unsigned short)0;
}

// ---------------- per-node gather-sum (16/4/1-deep MLP), R6-proven ----------
template<int F>
__device__ __forceinline__ void agg_range(const unsigned short* __restrict__ tab,
                                          const int* __restrict__ csr_src,
                                          int j, int hi, int lane, float* acc) {
    for (; j + 16 <= hi; j += 16) {
        int sidx[16];
#pragma unroll
        for (int u = 0; u < 16; ++u) sidx[u] = csr_src[j + u];
        if (F == 64) {
            unsigned short v[16];
#pragma unroll
            for (int u = 0; u < 16; ++u) v[u] = tab[(size_t)sidx[u] * 64 + lane];
#pragma unroll
            for (int u = 0; u < 16; ++u) acc[0] += bf2f(v[u]);
        } else if (F == 128) {
            ushort2 v[16];
#pragma unroll
            for (int u = 0; u < 16; ++u)
                v[u] = ((const ushort2*)(tab + (size_t)sidx[u] * F))[lane];
#pragma unroll
            for (int u = 0; u < 16; ++u) { acc[0] += bf2f(v[u].x); acc[1] += bf2f(v[u].y); }
        } else {
            ushort4 v[16];
#pragma unroll
            for (int u = 0; u < 16; ++u)
                v[u] = ((const ushort4*)(tab + (size_t)sidx[u] * F))[lane];
#pragma unroll
            for (int u = 0; u < 16; ++u) {
                acc[0] += bf2f(v[u].x); acc[1] += bf2f(v[u].y);
                acc[2] += bf2f(v[u].z); acc[3] += bf2f(v[u].w);
            }
        }
    }
    for (; j + 4 <= hi; j += 4) {
        int sidx[4];
#pragma unroll
        for (int u = 0; u < 4; ++u) sidx[u] = csr_src[j + u];
        if (F == 64) {
            unsigned short v[4];
#pragma unroll
            for (int u = 0; u < 4; ++u) v[u] = tab[(size_t)sidx[u] * 64 + lane];
#pragma unroll
            for (int u = 0; u < 4; ++u) acc[0] += bf2f(v[u]);
        } else if (F == 128) {
            ushort2 v[4];
#pragma unroll
            for (int u = 0; u < 4; ++u)
                v[u] = ((const ushort2*)(tab + (size_t)sidx[u] * F))[lane];
#pragma unroll
            for (int u = 0; u < 4; ++u) { acc[0] += bf2f(v[u].x); acc[1] += bf2f(v[u].y); }
        } else {
            ushort4 v[4];
#pragma unroll
            for (int u = 0; u < 4; ++u)
                v[u] = ((const ushort4*)(tab + (size_t)sidx[u] * F))[lane];
#pragma unroll
            for (int u = 0; u < 4; ++u) {
                acc[0] += bf2f(v[u].x); acc[1] += bf2f(v[u].y);
                acc[2] += bf2f(v[u].z); acc[3] += bf2f(v[u].w);
            }
        }
    }
    for (; j < hi; ++j) {
        int s = csr_src[j];
        if (F == 64) {
            acc[0] += bf2f(tab[(size_t)s * 64 + lane]);
        } else if (F == 128) {
            ushort2 u = ((const ushort2*)(tab + (size_t)s * F))[lane];
            acc[0] += bf2f(u.x); acc[1] += bf2f(u.y);
        } else {
            ushort4 u = ((const ushort4*)(tab + (size_t)s * F))[lane];
            acc[0] += bf2f(u.x); acc[1] += bf2f(u.y); acc[2] += bf2f(u.z); acc[3] += bf2f(u.w);
        }
    }
}

// ---------------- FUSED: agg (K-wide) -> LDS A-tile -> MFMA @ (Whi+Wlo)[K×N] + bias, relu
// Block = 32 output rows, 4 waves. 8 blocks/CU (LDS<=16KB, VGPR 44) so Phase-A
// (gather) of some blocks overlaps Phase-B (MFMA) of others.
// MODE 1: out = bf16(relu(acc+b)*dis[m]) (next gather table); MODE 2: out = bf16(relu(acc+b))
template<int K, int NTW, int N, int MODE>
__global__ __launch_bounds__(256, 8)
void fused_agg_gemm(const unsigned short* __restrict__ tab,
                    const int* __restrict__ csr_src,
                    const int* __restrict__ offsets,
                    const float* __restrict__ dis,
                    const unsigned short* __restrict__ Bhi,
                    const unsigned short* __restrict__ Blo,
                    const float* __restrict__ bias,
                    unsigned short* __restrict__ out) {
    constexpr int KS = K / 32;
    __shared__ unsigned short ldsA[32 * K];
    char* lb = (char*)ldsA;
    int l = threadIdx.x & 63;
    int w = threadIdx.x >> 6;      // 0..3
    int m0 = blockIdx.x * 32;

    // ---- Phase A: aggregate 8 nodes per wave ----
    for (int i = 0; i < 8; ++i) {
        int r = w * 8 + i;
        int n = m0 + r;
        float acc[(K + 63) / 64];
        if (K == 64) {
            acc[0] = bf2f(tab[(size_t)n * 64 + l]);
        } else if (K == 128) {
            ushort2 u = ((const ushort2*)(tab + (size_t)n * K))[l];
            acc[0] = bf2f(u.x); acc[1] = bf2f(u.y);
        } else {
            ushort4 u = ((const ushort4*)(tab + (size_t)n * K))[l];
            acc[0] = bf2f(u.x); acc[1] = bf2f(u.y); acc[2] = bf2f(u.z); acc[3] = bf2f(u.w);
        }
        agg_range<K>(tab, csr_src, offsets[n], offsets[n + 1], l, acc);
        float d = dis[n];
        unsigned sw = (unsigned)((r & 7) << 4);
        if (K == 64) {
            *(unsigned short*)(lb + ((unsigned)(r * 128 + l * 2) ^ sw)) = f2bf(d * acc[0]);
        } else if (K == 128) {
            ushort2 o; o.x = f2bf(d * acc[0]); o.y = f2bf(d * acc[1]);
            *(ushort2*)(lb + ((unsigned)(r * 256 + l * 4) ^ sw)) = o;
        } else {
            ushort4 o;
            o.x = f2bf(d * acc[0]); o.y = f2bf(d * acc[1]);
            o.z = f2bf(d * acc[2]); o.w = f2bf(d * acc[3]);
            *(ushort4*)(lb + ((unsigned)(r * 512 + l * 8) ^ sw)) = o;
        }
    }
    __syncthreads();

    // ---- Phase B: MFMA from LDS A ----
    int n0 = w * (NTW * 16);
    f32x4 acc0[NTW], acc1[NTW];
#pragma unroll
    for (int tn = 0; tn < NTW; ++tn) { acc0[tn] = (f32x4){0,0,0,0}; acc1[tn] = (f32x4){0,0,0,0}; }

    int r0 = l & 15, r1 = r0 + 16;
    unsigned sw0 = (unsigned)((r0 & 7) << 4);
#pragma unroll
    for (int s = 0; s < KS; ++s) {
        unsigned kb = (unsigned)(s * 64 + (l >> 4) * 16);
        bf16x8 af0 = *(const bf16x8*)(lb + ((unsigned)(r0 * K * 2 + kb) ^ sw0));
        bf16x8 af1 = *(const bf16x8*)(lb + ((unsigned)(r1 * K * 2 + kb) ^ sw0));
#pragma unroll
        for (int tn = 0; tn < NTW; ++tn) {
            int t = (n0 >> 4) + tn;
            size_t boff = ((size_t)(t * KS + s) * 64 + l) * 8;
            bf16x8 bh = *(const bf16x8*)(Bhi + boff);
            bf16x8 bl = *(const bf16x8*)(Blo + boff);
            acc0[tn] = __builtin_amdgcn_mfma_f32_16x16x32_bf16(af0, bh, acc0[tn], 0, 0, 0);
            acc0[tn] = __builtin_amdgcn_mfma_f32_16x16x32_bf16(af0, bl, acc0[tn], 0, 0, 0);
            acc1[tn] = __builtin_amdgcn_mfma_f32_16x16x32_bf16(af1, bh, acc1[tn], 0, 0, 0);
            acc1[tn] = __builtin_amdgcn_mfma_f32_16x16x32_bf16(af1, bl, acc1[tn], 0, 0, 0);
        }
    }

    int rowg = (l >> 4) * 4;
#pragma unroll
    for (int tn = 0; tn < NTW; ++tn) {
        int n = n0 + tn * 16 + (l & 15);
        float b = bias[n];
#pragma unroll
        for (int r = 0; r < 4; ++r) {
#pragma unroll
            for (int half = 0; half < 2; ++half) {
                int m = m0 + half * 16 + rowg + r;
                float v = fmaxf((half ? acc1[tn][r] : acc0[tn][r]) + b, 0.0f);
                if (MODE == 1) out[(size_t)m * N + n] = f2bf(v * dis[m]);
                else           out[(size_t)m * N + n] = f2bf(v);
            }
        }
    }
}

// ---------------- pooling (bf16 input, wave per graph) ----------------
__device__ __forceinline__ int lower_bound_dev(const int* __restrict__ a, int n, int key) {
    int lo = 0, hi = n;
    while (lo < hi) {
        int mid = (lo + hi) >> 1;
        if (a[mid] < key) lo = mid + 1; else hi = mid;
    }
    return lo;
}

__global__ __launch_bounds__(256, 4)
void pool_bf16_kernel(const unsigned short* __restrict__ h, const int* __restrict__ batch,
                      float* __restrict__ pooled) {
    int wave = threadIdx.x >> 6;
    int lane = threadIdx.x & 63;
    int g = blockIdx.x * 4 + wave;
    int lo = lower_bound_dev(batch, N_NODES, g);
    int hi = lower_bound_dev(batch, N_NODES, g + 1);
    float a0 = 0, a1 = 0, a2 = 0, a3 = 0;
    for (int n = lo; n < hi; ++n) {
        ushort4 u = ((const ushort4*)(h + (size_t)n * 256))[lane];
        a0 += bf2f(u.x); a1 += bf2f(u.y); a2 += bf2f(u.z); a3 += bf2f(u.w);
    }
    float inv = 1.0f / fmaxf((float)(hi - lo), 1.0f);
    float4 o = {a0 * inv, a1 * inv, a2 * inv, a3 * inv};
    *(float4*)&pooled[(size_t)g * 256 + lane * 4] = o;
}

// ---------------- head GEMM (fp32 naive, tiny M) ----------------
__global__ __launch_bounds__(256, 2)
void head_gemm_kernel(const float* __restrict__ H, const float* __restrict__ W,
                      const float* __restrict__ bias, float* __restrict__ out) {
    __shared__ float lds[16 * 256];
    int row0 = blockIdx.x * 16;
    int t = threadIdx.x;   // 0..255 (= col)
    const float* src = H + (size_t)row0 * 256;
    for (int i = t; i < 16 * 256; i += 256) lds[i] = src[i];
    __syncthreads();
    float acc[16];
#pragma unroll
    for (int r = 0; r < 16; ++r) acc[r] = 0.0f;
#pragma unroll 4
    for (int k = 0; k < 256; ++k) {
        float wv = W[k * 256 + t];
#pragma unroll
        for (int r = 0; r < 16; ++r) acc[r] += lds[r * 256 + k] * wv;
    }
#pragma unroll
    for (int r = 0; r < 16; ++r)
        out[(size_t)(row0 + r) * 256 + t] = acc[r] + bias[t];
}

// ---------------- launch ----------------
static inline size_t align_up(size_t x, size_t a) { return (x + a - 1) & ~(a - 1); }

extern "C" void kernel_launch(void* const* d_in, const int* in_sizes, int n_in,
                              void* d_out, int out_size, void* d_ws, size_t ws_size,
                              hipStream_t stream) {
    const float* x  = (const float*)d_in[0];
    const float* W1 = (const float*)d_in[1];
    const float* b1 = (const float*)d_in[2];
    const float* W2 = (const float*)d_in[3];
    const float* b2 = (const float*)d_in[4];
    const float* W3 = (const float*)d_in[5];
    const float* b3 = (const float*)d_in[6];
    const float* Wp = (const float*)d_in[7];
    const float* bp = (const float*)d_in[8];
    const int*   ei = (const int*)d_in[9];   // [2, E]
    const int*   batch = (const int*)d_in[10];
    float* out = (float*)d_out;

    const int* e_src = ei;
    const int* e_dst = ei + N_EDGES;

    char* p = (char*)d_ws;
    size_t off = 0;
    auto take = [&](size_t bytes) {
        void* r = p + off;
        off = align_up(off + bytes, 256);
        return r;
    };
    int*   hist        = (int*)  take(sizeof(int) * NB * NBLK);
    int*   tot         = (int*)  take(sizeof(int) * NB);
    int*   bucketStart = (int*)  take(sizeof(int) * (NB + 1));
    int*   offsets     = (int*)  take(sizeof(int) * (N_NODES + 1));
    int*   csr_src     = (int*)  take(sizeof(int) * N_EDGES);
    float* dis         = (float*)take(sizeof(float) * N_NODES);
    float* pooled      = (float*)take(sizeof(float) * N_GRAPHS * 256);
    unsigned short* whi1 = (unsigned short*)take(sizeof(unsigned short) * 64 * 128);
    unsigned short* wlo1 = (unsigned short*)take(sizeof(unsigned short) * 64 * 128);
    unsigned short* whi2 = (unsigned short*)take(sizeof(unsigned short) * 128 * 256);
    unsigned short* wlo2 = (unsigned short*)take(sizeof(unsigned short) * 128 * 256);
    unsigned short* whi3 = (unsigned short*)take(sizeof(unsigned short) * 256 * 256);
    unsigned short* wlo3 = (unsigned short*)take(sizeof(unsigned short) * 256 * 256);
    unsigned short* bufX = (unsigned short*)take(sizeof(unsigned short) * (size_t)N_NODES * 256);
    unsigned short* bufY = (unsigned short*)take(sizeof(unsigned short) * (size_t)N_NODES * 256);
    unsigned short* h3   = (unsigned short*)take(sizeof(unsigned short) * (size_t)N_NODES * 256);

    // CSR-build scratch aliases h3 (consumed in csr2 before h3 is written)
    int* spk = (int*)h3;   // packed (dlocal<<17|src), E ints = 12.8 MB

    // table plan: xb [100K×64] in bufY; table2 [100K×128] in bufX;
    // table3 [100K×256] in bufY (xb dead); h3 separate.
    unsigned short* xb     = bufY;
    unsigned short* table2 = bufX;
    unsigned short* table3 = bufY;

    // ---- CSR build via counting sort (no global atomics) ----
    hist_kernel<<<NBLK, 256, 0, stream>>>(e_dst, hist);
    bucket_tot_kernel<<<NB, 64, 0, stream>>>(hist, tot);
    bucket_scan_kernel<<<1, 256, 0, stream>>>(tot, bucketStart);
    bucket_base_kernel<<<(NB + 255) / 256, 256, 0, stream>>>(hist, bucketStart);
    scatter1_kernel<<<NBLK, 256, 0, stream>>>(e_src, e_dst, hist, spk);
    csr2_kernel<<<NB, 256, 0, stream>>>(spk, bucketStart, offsets, dis, csr_src);

    // pack weights into MFMA B-frag split-bf16 planes
    pack_w_kernel<64, 128><<<((128 / 16) * 2 * 64 + 255) / 256, 256, 0, stream>>>(W1, 37, whi1, wlo1);
    pack_w_kernel<128, 256><<<((256 / 16) * 4 * 64 + 255) / 256, 256, 0, stream>>>(W2, 128, whi2, wlo2);
    pack_w_kernel<256, 256><<<((256 / 16) * 8 * 64 + 255) / 256, 256, 0, stream>>>(W3, 256, whi3, wlo3);

    // Layer 1: xb = bf16(x*dis) pad64; table2 = bf16(relu(agg(xb)@W1 + b1) * dis)
    cast_x_kernel<<<(N_NODES * 64 + 255) / 256, 256, 0, stream>>>(x, dis, xb);
    fused_agg_gemm<64, 2, 128, 1><<<N_NODES / 32, 256, 0, stream>>>(
        xb, csr_src, offsets, dis, whi1, wlo1, b1, table2);

    // Layer 2: table3 = bf16(relu(agg(table2)@W2 + b2) * dis)
    fused_agg_gemm<128, 4, 256, 1><<<N_NODES / 32, 256, 0, stream>>>(
        table2, csr_src, offsets, dis, whi2, wlo2, b2, table3);

    // Layer 3: h3 = bf16(relu(agg(table3)@W3 + b3))
    fused_agg_gemm<256, 4, 256, 2><<<N_NODES / 32, 256, 0, stream>>>(
        table3, csr_src, offsets, dis, whi3, wlo3, b3, h3);

    // pool + head
    pool_bf16_kernel<<<N_GRAPHS / 4, 256, 0, stream>>>(h3, batch, pooled);
    head_gemm_kernel<<<N_GRAPHS / 16, 256, 0, stream>>>(pooled, Wp, bp, out);
}